// Round 3
// baseline (2721.516 us; speedup 1.0000x reference)
//
#include <hip/hip_runtime.h>
#include <hip/hip_bf16.h>

#define DD 32
#define EPSF 1e-16f

__device__ __forceinline__ float bf2f(unsigned int u16) {
    union { unsigned int i; float f; } v; v.i = u16 << 16; return v.f;
}
__device__ __forceinline__ void unpack2(unsigned int u, float& lo, float& hi) {
    union { unsigned int i; float f; } a, b;
    a.i = u << 16; b.i = u & 0xffff0000u;
    lo = a.f; hi = b.f;
}

// Load one D=32 row as fp32, from either a bf16 or an fp32 source buffer.
__device__ __forceinline__ void load_row(const void* base, size_t row, bool isbf,
                                         float xv[DD]) {
    if (isbf) {
        const uint4* r4 = reinterpret_cast<const uint4*>(
            (const unsigned short*)base + row * DD);
        uint4 a0 = r4[0], a1 = r4[1], a2 = r4[2], a3 = r4[3];
        unsigned int u[16] = {a0.x, a0.y, a0.z, a0.w, a1.x, a1.y, a1.z, a1.w,
                              a2.x, a2.y, a2.z, a2.w, a3.x, a3.y, a3.z, a3.w};
#pragma unroll
        for (int q = 0; q < 16; ++q) unpack2(u[q], xv[2 * q], xv[2 * q + 1]);
    } else {
        const float4* r4 = reinterpret_cast<const float4*>(
            (const float*)base + row * DD);
#pragma unroll
        for (int q = 0; q < 8; ++q) {
            float4 f = r4[q];
            xv[4 * q]     = f.x;
            xv[4 * q + 1] = f.y;
            xv[4 * q + 2] = f.z;
            xv[4 * q + 3] = f.w;
        }
    }
}

// ---- dtype probe: decode first 64 shorts of x as bf16; bf16 N(0,1) data has
// all magnitudes in [1e-12, 64); fp32 data decodes ~38/64 in-range. ----
__global__ void probe_kernel(const unsigned short* __restrict__ xs,
                             float* __restrict__ flag) {
    if (threadIdx.x == 0 && blockIdx.x == 0) {
        int cnt = 0;
        for (int i = 0; i < 64; ++i) {
            float a = fabsf(bf2f(xs[i]));
            if (a == 0.0f || (a > 1e-12f && a < 64.0f)) ++cnt;
        }
        *flag = (cnt >= 52) ? 1.0f : 0.0f;  // 1 = bf16, 0 = fp32
    }
}

// ---- weights -> fp32 in workspace ----
__global__ void convert_weights_kernel(const void* __restrict__ W_emb,
                                       const void* __restrict__ b_emb,
                                       const void* __restrict__ W_score,
                                       const void* __restrict__ b_score,
                                       const float* __restrict__ flag,
                                       float* __restrict__ Wf, float* __restrict__ bfv,
                                       float* __restrict__ Wsf, float* __restrict__ bsf) {
    bool isbf = (*flag > 0.5f);
    int t = threadIdx.x;
    if (isbf) {
        const unsigned short* W  = (const unsigned short*)W_emb;
        const unsigned short* be = (const unsigned short*)b_emb;
        const unsigned short* Ws = (const unsigned short*)W_score;
        const unsigned short* bs = (const unsigned short*)b_score;
        for (int i = t; i < DD * DD; i += blockDim.x) Wf[i] = bf2f(W[i]);
        if (t < DD) { bfv[t] = bf2f(be[t]); Wsf[t] = bf2f(Ws[t]); }
        if (t == 0) bsf[0] = bf2f(bs[0]);
    } else {
        const float* W  = (const float*)W_emb;
        const float* be = (const float*)b_emb;
        const float* Ws = (const float*)W_score;
        const float* bs = (const float*)b_score;
        for (int i = t; i < DD * DD; i += blockDim.x) Wf[i] = W[i];
        if (t < DD) { bfv[t] = be[t]; Wsf[t] = Ws[t]; }
        if (t == 0) bsf[0] = bs[0];
    }
}

// ---- per-edge score -> ex, atomic denom ----
__global__ void score_kernel(const void* __restrict__ ax,
                             const int* __restrict__ index,
                             const float* __restrict__ flag,
                             const float* __restrict__ Wsf, const float* __restrict__ bsf,
                             float* __restrict__ ex, float* __restrict__ denom, int E) {
    int e = blockIdx.x * blockDim.x + threadIdx.x;
    if (e >= E) return;
    bool isbf = (*flag > 0.5f);
    float xv[DD];
    load_row(ax, (size_t)e, isbf, xv);
    float s = bsf[0];
#pragma unroll
    for (int k = 0; k < DD; ++k) s = fmaf(xv[k], Wsf[k], s);
    float exv = __expf(s);
    ex[e] = exv;
    unsafeAtomicAdd(&denom[index[e]], exv);
}

// ---- per-edge embed (x @ W + b), weight, scatter-add directly into fp32 out ----
__launch_bounds__(256)
__global__ void agg_kernel(const void* __restrict__ x,
                           const int* __restrict__ index,
                           const float* __restrict__ flag,
                           const float* __restrict__ ex, const float* __restrict__ denom,
                           const float* __restrict__ Wf, const float* __restrict__ bfv,
                           float* __restrict__ out, int E) {
    int e = blockIdx.x * blockDim.x + threadIdx.x;
    if (e >= E) return;
    bool isbf = (*flag > 0.5f);
    int idx = index[e];
    float w = ex[e] / (denom[idx] + EPSF);

    float xv[DD];
    load_row(x, (size_t)e, isbf, xv);

    float h[DD];
#pragma unroll
    for (int i = 0; i < DD; ++i) h[i] = bfv[i];
#pragma unroll
    for (int k = 0; k < DD; ++k) {
        float xk = xv[k];
#pragma unroll
        for (int i = 0; i < DD; ++i) h[i] = fmaf(xk, Wf[k * DD + i], h[i]);
    }

    float* orow = out + (size_t)idx * DD;
#pragma unroll
    for (int i = 0; i < DD; ++i) unsafeAtomicAdd(&orow[i], h[i] * w);
}

extern "C" void kernel_launch(void* const* d_in, const int* in_sizes, int n_in,
                              void* d_out, int out_size, void* d_ws, size_t ws_size,
                              hipStream_t stream) {
    const void* x       = d_in[0];
    const void* ax      = d_in[1];
    const int*  index   = (const int*)d_in[2];
    // d_in[3] = size (scalar) — N derived from out_size instead
    const void* W_emb   = d_in[4];
    const void* b_emb   = d_in[5];
    const void* W_score = d_in[6];
    const void* b_score = d_in[7];

    int E = in_sizes[0] / DD;
    int N = out_size / DD;

    float* ws_f  = (float*)d_ws;
    float* flag  = ws_f;                        // [1]
    float* denom = flag + 1;                    // [N]
    float* Wf    = denom + (size_t)N;           // [DD*DD]
    float* bfv   = Wf + DD * DD;                // [DD]
    float* Wsf   = bfv + DD;                    // [DD]
    float* bsf   = Wsf + DD;                    // [1]
    float* ex    = bsf + 1;                     // [E]

    probe_kernel<<<1, 64, 0, stream>>>((const unsigned short*)x, flag);

    // zero denom and the fp32 output accumulator (harness only memsets d_out
    // before the correctness call, not between timed replays)
    hipMemsetAsync(denom, 0, sizeof(float) * (size_t)N, stream);
    hipMemsetAsync(d_out, 0, sizeof(float) * (size_t)out_size, stream);

    convert_weights_kernel<<<1, 256, 0, stream>>>(W_emb, b_emb, W_score, b_score,
                                                  flag, Wf, bfv, Wsf, bsf);

    int blocks = (E + 255) / 256;
    score_kernel<<<blocks, 256, 0, stream>>>(ax, index, flag, Wsf, bsf, ex, denom, E);
    agg_kernel<<<blocks, 256, 0, stream>>>(x, index, flag, ex, denom, Wf, bfv,
                                           (float*)d_out, E);
}

// Round 4
// 440.598 us; speedup vs baseline: 6.1769x; 6.1769x over previous
//
#include <hip/hip_runtime.h>
#include <hip/hip_bf16.h>

#define DD 32
#define EPSF 1e-16f
#define SCAN_T 1024

// ---- kernel 1: per-edge score -> ex[e] = exp(s_e); histogram of index ----
__global__ void score_hist_kernel(const float* __restrict__ ax,
                                  const int* __restrict__ index,
                                  const float* __restrict__ Wsf,
                                  const float* __restrict__ bsf,
                                  float* __restrict__ ex, int* __restrict__ cnt,
                                  int E) {
    int e = blockIdx.x * blockDim.x + threadIdx.x;
    if (e >= E) return;
    const float4* r4 = reinterpret_cast<const float4*>(ax + (size_t)e * DD);
    float s = bsf[0];
#pragma unroll
    for (int q = 0; q < 8; ++q) {
        float4 f = r4[q];
        s = fmaf(f.x, Wsf[4 * q],     s);
        s = fmaf(f.y, Wsf[4 * q + 1], s);
        s = fmaf(f.z, Wsf[4 * q + 2], s);
        s = fmaf(f.w, Wsf[4 * q + 3], s);
    }
    ex[e] = __expf(s);
    atomicAdd(&cnt[index[e]], 1);
}

// ---- kernel 2: exclusive scan of cnt[N] -> off[N+1], copy into cursor ----
__global__ void scan_kernel(const int* __restrict__ cnt, int* __restrict__ off,
                            int* __restrict__ cursor, int N) {
    __shared__ int part[SCAN_T];
    int t = threadIdx.x;
    int chunk = (N + SCAN_T - 1) / SCAN_T;
    int lo = t * chunk;
    int hi = min(lo + chunk, N);
    int s = 0;
    for (int i = lo; i < hi; ++i) s += cnt[i];
    part[t] = s;
    __syncthreads();
    // Hillis-Steele inclusive scan over the 1024 partials
    for (int d = 1; d < SCAN_T; d <<= 1) {
        int v = (t >= d) ? part[t - d] : 0;
        __syncthreads();
        part[t] += v;
        __syncthreads();
    }
    int run = (t == 0) ? 0 : part[t - 1];  // exclusive prefix of this chunk
    for (int i = lo; i < hi; ++i) {
        off[i] = run;
        cursor[i] = run;
        run += cnt[i];
    }
    if (t == SCAN_T - 1) off[N] = run;  // == E
}

// ---- kernel 3: scatter edge ids into segment-sorted order ----
__global__ void scatter_kernel(const int* __restrict__ index,
                               int* __restrict__ cursor,
                               int* __restrict__ sorted_eid, int E) {
    int e = blockIdx.x * blockDim.x + threadIdx.x;
    if (e >= E) return;
    int pos = atomicAdd(&cursor[index[e]], 1);
    sorted_eid[pos] = e;
}

// ---- kernel 4: one wave per node — gather, normalize, apply W, write row ----
__launch_bounds__(256)
__global__ void gather_kernel(const float* __restrict__ x,
                              const float* __restrict__ ex,
                              const int* __restrict__ off,
                              const int* __restrict__ sorted_eid,
                              const float* __restrict__ Wf,   // [DD][DD] row-major
                              const float* __restrict__ bfv,  // [DD]
                              float* __restrict__ out, int N) {
    int n = blockIdx.x * 4 + (threadIdx.x >> 6);
    if (n >= N) return;
    int lane = threadIdx.x & 63;
    int half = lane >> 5;   // which of 2 edges per iteration
    int k = lane & 31;      // feature element

    int beg = off[n], end = off[n + 1];
    float yacc = 0.0f, dacc = 0.0f;
    for (int p = beg + half; p < end; p += 2) {
        int eid = sorted_eid[p];
        float exv = ex[eid];
        float xval = x[(size_t)eid * DD + k];
        yacc = fmaf(exv, xval, yacc);
        dacc += exv;
    }
    // combine the two half-wave accumulators
    yacc += __shfl_xor(yacc, 32);
    dacc += __shfl_xor(dacc, 32);

    float d = dacc;
    float ynorm = yacc / (d + EPSF);      // (Σ ex·x)/(denom+eps) element k
    float sw = d / (d + EPSF);            // Σ w_e

    // out[n][k] = sw*b[k] + Σ_kk ynorm[kk] * W[kk][k]
    float o = sw * bfv[k];
#pragma unroll
    for (int kk = 0; kk < DD; ++kk) {
        float yk = __shfl(ynorm, kk);     // broadcast element kk
        o = fmaf(yk, Wf[kk * DD + k], o);
    }
    if (half == 0) out[(size_t)n * DD + k] = o;
}

extern "C" void kernel_launch(void* const* d_in, const int* in_sizes, int n_in,
                              void* d_out, int out_size, void* d_ws, size_t ws_size,
                              hipStream_t stream) {
    const float* x       = (const float*)d_in[0];
    const float* ax      = (const float*)d_in[1];
    const int*   index   = (const int*)d_in[2];
    // d_in[3] = size scalar; N derived from out_size
    const float* W_emb   = (const float*)d_in[4];
    const float* b_emb   = (const float*)d_in[5];
    const float* W_score = (const float*)d_in[6];
    const float* b_score = (const float*)d_in[7];

    int E = in_sizes[0] / DD;
    int N = out_size / DD;

    // workspace layout
    float* ex         = (float*)d_ws;                 // [E]
    int*   cnt        = (int*)(ex + (size_t)E);       // [N]
    int*   off        = cnt + (size_t)N;              // [N+1]
    int*   cursor     = off + (size_t)N + 1;          // [N]
    int*   sorted_eid = cursor + (size_t)N;           // [E]

    hipMemsetAsync(cnt, 0, sizeof(int) * (size_t)N, stream);

    int blocksE = (E + 255) / 256;
    score_hist_kernel<<<blocksE, 256, 0, stream>>>(ax, index, W_score, b_score,
                                                   ex, cnt, E);
    scan_kernel<<<1, SCAN_T, 0, stream>>>(cnt, off, cursor, N);
    scatter_kernel<<<blocksE, 256, 0, stream>>>(index, cursor, sorted_eid, E);

    int blocksN = (N + 3) / 4;  // 4 waves (nodes) per 256-thread block
    gather_kernel<<<blocksN, 256, 0, stream>>>(x, ex, off, sorted_eid,
                                               W_emb, b_emb, (float*)d_out, N);
}

// Round 5
// 390.484 us; speedup vs baseline: 6.9696x; 1.1283x over previous
//
#include <hip/hip_runtime.h>
#include <hip/hip_bf16.h>

#define DD 32
#define EPSF 1e-16f
#define SCAN_T 1024

// ---- kernel 1: per-edge score -> ex[e] = exp(s_e); histogram of index ----
// 2 edges per thread for memory-level parallelism.
__global__ void score_hist_kernel(const float* __restrict__ ax,
                                  const int* __restrict__ index,
                                  const float* __restrict__ Wsf,
                                  const float* __restrict__ bsf,
                                  float* __restrict__ ex, int* __restrict__ cnt,
                                  int E) {
    int i = blockIdx.x * blockDim.x + threadIdx.x;
    int e0 = i * 2;
    if (e0 >= E) return;
    bool two = (e0 + 1 < E);
    int e1 = two ? e0 + 1 : e0;  // clamped (safe re-read, result discarded)

    const float4* r0 = reinterpret_cast<const float4*>(ax + (size_t)e0 * DD);
    const float4* r1 = reinterpret_cast<const float4*>(ax + (size_t)e1 * DD);
    float b = bsf[0];
    float s0 = b, s1 = b;
#pragma unroll
    for (int q = 0; q < 8; ++q) {
        float4 f0 = r0[q];
        float4 f1 = r1[q];
        float w0 = Wsf[4 * q], w1 = Wsf[4 * q + 1];
        float w2 = Wsf[4 * q + 2], w3 = Wsf[4 * q + 3];
        s0 = fmaf(f0.x, w0, s0); s0 = fmaf(f0.y, w1, s0);
        s0 = fmaf(f0.z, w2, s0); s0 = fmaf(f0.w, w3, s0);
        s1 = fmaf(f1.x, w0, s1); s1 = fmaf(f1.y, w1, s1);
        s1 = fmaf(f1.z, w2, s1); s1 = fmaf(f1.w, w3, s1);
    }
    float ex0 = __expf(s0), ex1 = __expf(s1);
    if (two) {
        reinterpret_cast<float2*>(ex)[i] = make_float2(ex0, ex1);
        atomicAdd(&cnt[index[e0]], 1);
        atomicAdd(&cnt[index[e1]], 1);
    } else {
        ex[e0] = ex0;
        atomicAdd(&cnt[index[e0]], 1);
    }
}

// ---- kernel 2: exclusive scan of cnt[N] -> off[N+1], copy into cursor ----
__global__ void scan_kernel(const int* __restrict__ cnt, int* __restrict__ off,
                            int* __restrict__ cursor, int N) {
    __shared__ int part[SCAN_T];
    int t = threadIdx.x;
    int chunk = (N + SCAN_T - 1) / SCAN_T;
    int lo = t * chunk;
    int hi = min(lo + chunk, N);
    int s = 0;
    for (int i = lo; i < hi; ++i) s += cnt[i];
    part[t] = s;
    __syncthreads();
    for (int d = 1; d < SCAN_T; d <<= 1) {
        int v = (t >= d) ? part[t - d] : 0;
        __syncthreads();
        part[t] += v;
        __syncthreads();
    }
    int run = (t == 0) ? 0 : part[t - 1];
    for (int i = lo; i < hi; ++i) {
        off[i] = run;
        cursor[i] = run;
        run += cnt[i];
    }
    if (t == SCAN_T - 1) off[N] = run;  // == E
}

// ---- kernel 3: scatter (eid, ex) pairs into segment-sorted order ----
template <bool PAIRED>
__global__ void scatter_kernel(const int* __restrict__ index,
                               const float* __restrict__ ex,
                               int* __restrict__ cursor,
                               uint2* __restrict__ pairs,
                               int* __restrict__ sorted_eid, int E) {
    int e = blockIdx.x * blockDim.x + threadIdx.x;
    if (e >= E) return;
    int pos = atomicAdd(&cursor[index[e]], 1);
    if (PAIRED) {
        pairs[pos] = make_uint2((unsigned)e, __float_as_uint(ex[e]));
    } else {
        sorted_eid[pos] = e;
    }
}

// ---- kernel 4: one wave per node — gather (unroll x4), normalize, apply W ----
template <bool PAIRED>
__launch_bounds__(256)
__global__ void gather_kernel(const float* __restrict__ x,
                              const float* __restrict__ ex,
                              const uint2* __restrict__ pairs,
                              const int* __restrict__ sorted_eid,
                              const int* __restrict__ off,
                              const float* __restrict__ Wf,   // [DD][DD] row-major
                              const float* __restrict__ bfv,  // [DD]
                              float* __restrict__ out, int N) {
    int n = blockIdx.x * 4 + (threadIdx.x >> 6);
    if (n >= N) return;
    int lane = threadIdx.x & 63;
    int half = lane >> 5;   // 2 edges per wave-iteration slot
    int k = lane & 31;      // feature element

    int beg = off[n], end = off[n + 1];
    float yacc = 0.0f, dacc = 0.0f;
    int p = beg + half;
    // unrolled: each half handles 4 edges per iteration (wave: 8 edges)
    for (; p + 6 < end; p += 8) {
        unsigned e0, e1, e2, e3;
        float w0, w1, w2, w3;
        if (PAIRED) {
            uint2 a0 = pairs[p],     a1 = pairs[p + 2];
            uint2 a2 = pairs[p + 4], a3 = pairs[p + 6];
            e0 = a0.x; w0 = __uint_as_float(a0.y);
            e1 = a1.x; w1 = __uint_as_float(a1.y);
            e2 = a2.x; w2 = __uint_as_float(a2.y);
            e3 = a3.x; w3 = __uint_as_float(a3.y);
        } else {
            e0 = sorted_eid[p];     e1 = sorted_eid[p + 2];
            e2 = sorted_eid[p + 4]; e3 = sorted_eid[p + 6];
            w0 = ex[e0]; w1 = ex[e1]; w2 = ex[e2]; w3 = ex[e3];
        }
        float x0 = x[(size_t)e0 * DD + k];
        float x1 = x[(size_t)e1 * DD + k];
        float x2 = x[(size_t)e2 * DD + k];
        float x3 = x[(size_t)e3 * DD + k];
        yacc = fmaf(w0, x0, yacc);
        yacc = fmaf(w1, x1, yacc);
        yacc = fmaf(w2, x2, yacc);
        yacc = fmaf(w3, x3, yacc);
        dacc += (w0 + w1) + (w2 + w3);
    }
    for (; p < end; p += 2) {
        unsigned e; float w;
        if (PAIRED) {
            uint2 a = pairs[p];
            e = a.x; w = __uint_as_float(a.y);
        } else {
            e = sorted_eid[p]; w = ex[e];
        }
        yacc = fmaf(w, x[(size_t)e * DD + k], yacc);
        dacc += w;
    }
    yacc += __shfl_xor(yacc, 32);
    dacc += __shfl_xor(dacc, 32);

    float d = dacc;
    float ynorm = yacc / (d + EPSF);      // (Σ ex·x)/(denom+eps), element k
    float sw = d / (d + EPSF);            // Σ w_e

    float o = sw * bfv[k];
#pragma unroll
    for (int kk = 0; kk < DD; ++kk) {
        o = fmaf(__shfl(ynorm, kk), Wf[kk * DD + k], o);
    }
    if (half == 0) out[(size_t)n * DD + k] = o;
}

extern "C" void kernel_launch(void* const* d_in, const int* in_sizes, int n_in,
                              void* d_out, int out_size, void* d_ws, size_t ws_size,
                              hipStream_t stream) {
    const float* x       = (const float*)d_in[0];
    const float* ax      = (const float*)d_in[1];
    const int*   index   = (const int*)d_in[2];
    // d_in[3] = size scalar; N derived from out_size
    const float* W_emb   = (const float*)d_in[4];
    const float* b_emb   = (const float*)d_in[5];
    const float* W_score = (const float*)d_in[6];
    const float* b_score = (const float*)d_in[7];

    int E = in_sizes[0] / DD;
    int N = out_size / DD;

    size_t need_paired = (size_t)E * 8 + (size_t)E * 4 + ((size_t)N * 3 + 2) * 4;
    bool paired = ws_size >= need_paired;

    // workspace layout
    uint2* pairs      = (uint2*)d_ws;                              // [E] (paired only)
    float* ex         = paired ? (float*)(pairs + (size_t)E)
                               : (float*)d_ws;                     // [E]
    int*   sorted_eid = paired ? nullptr
                               : (int*)(ex + (size_t)E);           // [E] (fallback)
    int*   cnt        = paired ? (int*)(ex + (size_t)E)
                               : sorted_eid + (size_t)E;           // [N]
    int*   off        = cnt + (size_t)N;                           // [N+1]
    int*   cursor     = off + (size_t)N + 1;                       // [N]

    hipMemsetAsync(cnt, 0, sizeof(int) * (size_t)N, stream);

    int blocksE2 = ((E + 1) / 2 + 255) / 256;
    score_hist_kernel<<<blocksE2, 256, 0, stream>>>(ax, index, W_score, b_score,
                                                    ex, cnt, E);
    scan_kernel<<<1, SCAN_T, 0, stream>>>(cnt, off, cursor, N);

    int blocksE = (E + 255) / 256;
    int blocksN = (N + 3) / 4;
    if (paired) {
        scatter_kernel<true><<<blocksE, 256, 0, stream>>>(index, ex, cursor,
                                                          pairs, nullptr, E);
        gather_kernel<true><<<blocksN, 256, 0, stream>>>(x, ex, pairs, nullptr, off,
                                                         W_emb, b_emb,
                                                         (float*)d_out, N);
    } else {
        scatter_kernel<false><<<blocksE, 256, 0, stream>>>(index, ex, cursor,
                                                           nullptr, sorted_eid, E);
        gather_kernel<false><<<blocksN, 256, 0, stream>>>(x, ex, nullptr, sorted_eid,
                                                          off, W_emb, b_emb,
                                                          (float*)d_out, N);
    }
}